// Round 4
// baseline (1829.751 us; speedup 1.0000x reference)
//
#include <hip/hip_runtime.h>

#define NX 128
#define NSTEPS 4096

template <int CTRL>
__device__ __forceinline__ float dpp_mov_f(float v) {
  int i = __float_as_int(v);
  return __int_as_float(__builtin_amdgcn_update_dpp(i, i, CTRL, 0xf, 0xf, false));
}

__launch_bounds__(256, 1)
__global__ void nmpc_rollout_kernel(const float* __restrict__ x0,
                                    const float* __restrict__ xref,
                                    const float* __restrict__ useq,
                                    const float* __restrict__ A,
                                    const float* __restrict__ B,
                                    float* __restrict__ out) {
  __shared__ __align__(16) float xbuf0[NX];
  __shared__ __align__(16) float xbuf1[NX];
  __shared__ double wsum[4];

  const int t = threadIdx.x;
  const int r = t >> 1;      // row 0..127 (2 threads per row)
  const int p = t & 1;       // column half 0..1 (64 cols each)
  const bool lead = (p == 0);

  // A fragment: row r, cols p*64 .. p*64+63 -> 16 float4 = 64 VGPRs
  float4 a[16];
#pragma unroll
  for (int q = 0; q < 16; ++q) {
    a[q] = *(const float4*)(A + r * NX + p * 64 + q * 4);
  }

  const float b0 = B[2 * r];
  const float b1 = B[2 * r + 1];

  // fp64 state on lead lanes (fp32 state-storage rounding was the dominant
  // error term); LDS holds the fp32 copy used by the matvec.
  double x_cur = (double)x0[r];
  double mse = 0.0;
  if (lead) {
    double d = x_cur - (double)xref[r];
    mse = d * d;
    xbuf0[r] = (float)x_cur;
  }
  asm volatile("s_waitcnt lgkmcnt(0)" ::: "memory");
  __builtin_amdgcn_s_barrier();
  asm volatile("" ::: "memory");

  // one-step-ahead prefetch (stays in flight across the raw barrier —
  // no vmcnt(0) drain in the loop)
  float xr = xref[NX + r];
  float u0 = useq[0];
  float u1 = useq[NSTEPS];

  auto step = [&](const float* __restrict__ src, float* __restrict__ dst, int s) {
    // ---- prefetch next step's operands ----
    int nref = (s + 2 <= NSTEPS) ? (s + 2) : NSTEPS;
    float xr_next = xref[nref * NX + r];
    int nu = (s + 1 <= NSTEPS - 1) ? (s + 1) : (NSTEPS - 1);
    float u0n = useq[nu];
    float u1n = useq[NSTEPS + nu];

    // ---- read x half-slice from LDS (2 distinct addrs/inst: free) ----
    const float4* xb = (const float4*)(src + p * 64);
    float acc[4] = {0.f, 0.f, 0.f, 0.f};
#pragma unroll
    for (int q = 0; q < 16; ++q) {
      float4 xv = xb[q];
      float4 av = a[q];
      acc[q & 3] = fmaf(av.x, xv.x, acc[q & 3]);
      acc[q & 3] = fmaf(av.y, xv.y, acc[q & 3]);
      acc[q & 3] = fmaf(av.z, xv.z, acc[q & 3]);
      acc[q & 3] = fmaf(av.w, xv.w, acc[q & 3]);
    }
    float sum = (acc[0] + acc[1]) + (acc[2] + acc[3]);
    sum += dpp_mov_f<0xB1>(sum);  // quad_perm [1,0,3,2]: xor1 — full row dot

    if (lead) {
      float zf = fmaf(b1, u1, fmaf(b0, u0, sum));
      zf = fminf(fmaxf(zf, -15.f), 15.f);
      float e = __builtin_amdgcn_exp2f(zf * 2.8853900817779268f);  // e^{2z}
      float xd = (e - 1.f) * __builtin_amdgcn_rcpf(e + 1.f);       // tanh(z)
      x_cur += (double)xd;
      dst[r] = (float)x_cur;
      double d = x_cur - (double)xr;
      mse += d * d;
    }
    // raw barrier: only lgkmcnt drains; prefetch loads remain in flight
    asm volatile("s_waitcnt lgkmcnt(0)" ::: "memory");
    __builtin_amdgcn_s_barrier();
    asm volatile("" ::: "memory");

    xr = xr_next;
    u0 = u0n;
    u1 = u1n;
  };

#pragma unroll 1
  for (int s = 0; s < NSTEPS; s += 2) {
    step(xbuf0, xbuf1, s);
    step(xbuf1, xbuf0, s + 1);
  }

  // ---- final reduction of the MSE accumulator (outside the hot loop) ----
#pragma unroll
  for (int off = 1; off < 64; off <<= 1) mse += __shfl_xor(mse, off, 64);
  if ((t & 63) == 0) wsum[t >> 6] = mse;
  __syncthreads();
  if (t == 0) {
    double tot = wsum[0] + wsum[1] + wsum[2] + wsum[3];
    out[0] = (float)(tot / (double)((NSTEPS + 1) * NX));
  }
}

extern "C" void kernel_launch(void* const* d_in, const int* in_sizes, int n_in,
                              void* d_out, int out_size, void* d_ws, size_t ws_size,
                              hipStream_t stream) {
  const float* x0 = (const float*)d_in[0];
  const float* xref = (const float*)d_in[1];
  const float* useq = (const float*)d_in[2];
  const float* A = (const float*)d_in[3];
  const float* B = (const float*)d_in[4];
  float* out = (float*)d_out;

  nmpc_rollout_kernel<<<dim3(1), dim3(256), 0, stream>>>(x0, xref, useq, A, B, out);
}

// Round 5
// 1450.815 us; speedup vs baseline: 1.2612x; 1.2612x over previous
//
#include <hip/hip_runtime.h>

#define NX 128
#define NSTEPS 4096

// v += DPP-moved v. bound_ctrl=false: invalid source lanes keep old value
// (harmless: only lanes p>=4 are consumed after the final stage).
template <int CTRL>
__device__ __forceinline__ float dpp_add_f(float v) {
  int i = __float_as_int(v);
  int s = __builtin_amdgcn_update_dpp(i, i, CTRL, 0xf, 0xf, false);
  return v + __int_as_float(s);
}

__launch_bounds__(256, 1)
__global__ void nmpc_rollout_kernel(const float* __restrict__ x0,
                                    const float* __restrict__ xref,
                                    const float* __restrict__ useq,
                                    const float* __restrict__ A,
                                    const float* __restrict__ B,
                                    float* __restrict__ out) {
  // x stored as 8 slices of 16 floats padded to 20 words (80B stride):
  // per ds_read_b128 the 8 broadcast groups start at banks
  // (20p)%32 = {0,20,8,28,16,4,24,12} -> disjoint bank quads, conflict-free.
  __shared__ __align__(16) float xs0[160];
  __shared__ __align__(16) float xs1[160];
  __shared__ float2 us[NSTEPS];  // interleaved (u0[s], u1[s]) pairs, 32KB
  __shared__ double wsum[4];

  const int t = threadIdx.x;
  const int g = t >> 3;        // row-group 0..31 (4 rows each)
  const int p = t & 7;         // column part 0..7 (16 cols each)
  const int j0 = p & 3;        // row-within-group owned by tail lanes
  const int r = 4 * g + j0;    // row index (valid 0..127 on every lane)
  const bool tail = (p >= 4);  // row_shr:4 delivers the full sum to lanes 4..7

  // ---- one-time staging of useq into LDS (interleaved pairs) ----
#pragma unroll
  for (int k = 0; k < NSTEPS / 256; ++k) {
    int idx = k * 256 + t;
    us[idx] = make_float2(useq[idx], useq[NSTEPS + idx]);
  }

  // ---- A fragment: rows 4g..4g+3, cols 16p..16p+15 -> 64 VGPRs ----
  float4 a[4][4];
#pragma unroll
  for (int j = 0; j < 4; ++j) {
#pragma unroll
    for (int q = 0; q < 4; ++q) {
      a[j][q] = *(const float4*)(A + (4 * g + j) * NX + 16 * p + 4 * q);
    }
  }

  const float b0 = B[2 * r];
  const float b1 = B[2 * r + 1];

  // fp64 state on tail lanes; LDS holds the fp32 copy used by the matvec.
  double x_cur = (double)x0[r];
  double mse = 0.0;
  if (tail) {
    double d = x_cur - (double)xref[r];
    mse = d * d;
    xs0[20 * (r >> 4) + (r & 15)] = (float)x_cur;  // 128 writers, once each
  }
  asm volatile("s_waitcnt lgkmcnt(0)" ::: "memory");
  __builtin_amdgcn_s_barrier();
  asm volatile("" ::: "memory");

  // ---- 4-deep rolling prefetch of xref rows (consumed off the x-chain) ----
  float xr0 = xref[1 * NX + r];
  float xr1 = xref[2 * NX + r];
  float xr2 = xref[3 * NX + r];
  float xr3 = xref[4 * NX + r];

  auto step = [&](const float* __restrict__ src, float* __restrict__ dst, int s) {
    // broadcast u pair (same addr across wave: free); hidden under FMAs
    float2 uv = us[s];
    // refill prefetch slot 3 (row for step s+4's residual)
    int nref = (s + 5 <= NSTEPS) ? (s + 5) : NSTEPS;
    float xnew = xref[nref * NX + r];

    // ---- read own 16-col x slice (4x ds_read_b128, conflict-free) ----
    const float4* xb = (const float4*)(src + 20 * p);
    float4 xv0 = xb[0], xv1 = xb[1], xv2 = xb[2], xv3 = xb[3];

    // ---- 4 rows x 16 cols partial dots (4 independent chains) ----
    float acc0 = 0.f, acc1 = 0.f, acc2 = 0.f, acc3 = 0.f;
#pragma unroll
    for (int j = 0; j < 1; ++j) { /* keep scope flat */ }
    {
      acc0 = fmaf(a[0][0].x, xv0.x, acc0); acc0 = fmaf(a[0][0].y, xv0.y, acc0);
      acc0 = fmaf(a[0][0].z, xv0.z, acc0); acc0 = fmaf(a[0][0].w, xv0.w, acc0);
      acc0 = fmaf(a[0][1].x, xv1.x, acc0); acc0 = fmaf(a[0][1].y, xv1.y, acc0);
      acc0 = fmaf(a[0][1].z, xv1.z, acc0); acc0 = fmaf(a[0][1].w, xv1.w, acc0);
      acc0 = fmaf(a[0][2].x, xv2.x, acc0); acc0 = fmaf(a[0][2].y, xv2.y, acc0);
      acc0 = fmaf(a[0][2].z, xv2.z, acc0); acc0 = fmaf(a[0][2].w, xv2.w, acc0);
      acc0 = fmaf(a[0][3].x, xv3.x, acc0); acc0 = fmaf(a[0][3].y, xv3.y, acc0);
      acc0 = fmaf(a[0][3].z, xv3.z, acc0); acc0 = fmaf(a[0][3].w, xv3.w, acc0);

      acc1 = fmaf(a[1][0].x, xv0.x, acc1); acc1 = fmaf(a[1][0].y, xv0.y, acc1);
      acc1 = fmaf(a[1][0].z, xv0.z, acc1); acc1 = fmaf(a[1][0].w, xv0.w, acc1);
      acc1 = fmaf(a[1][1].x, xv1.x, acc1); acc1 = fmaf(a[1][1].y, xv1.y, acc1);
      acc1 = fmaf(a[1][1].z, xv1.z, acc1); acc1 = fmaf(a[1][1].w, xv1.w, acc1);
      acc1 = fmaf(a[1][2].x, xv2.x, acc1); acc1 = fmaf(a[1][2].y, xv2.y, acc1);
      acc1 = fmaf(a[1][2].z, xv2.z, acc1); acc1 = fmaf(a[1][2].w, xv2.w, acc1);
      acc1 = fmaf(a[1][3].x, xv3.x, acc1); acc1 = fmaf(a[1][3].y, xv3.y, acc1);
      acc1 = fmaf(a[1][3].z, xv3.z, acc1); acc1 = fmaf(a[1][3].w, xv3.w, acc1);

      acc2 = fmaf(a[2][0].x, xv0.x, acc2); acc2 = fmaf(a[2][0].y, xv0.y, acc2);
      acc2 = fmaf(a[2][0].z, xv0.z, acc2); acc2 = fmaf(a[2][0].w, xv0.w, acc2);
      acc2 = fmaf(a[2][1].x, xv1.x, acc2); acc2 = fmaf(a[2][1].y, xv1.y, acc2);
      acc2 = fmaf(a[2][1].z, xv1.z, acc2); acc2 = fmaf(a[2][1].w, xv1.w, acc2);
      acc2 = fmaf(a[2][2].x, xv2.x, acc2); acc2 = fmaf(a[2][2].y, xv2.y, acc2);
      acc2 = fmaf(a[2][2].z, xv2.z, acc2); acc2 = fmaf(a[2][2].w, xv2.w, acc2);
      acc2 = fmaf(a[2][3].x, xv3.x, acc2); acc2 = fmaf(a[2][3].y, xv3.y, acc2);
      acc2 = fmaf(a[2][3].z, xv3.z, acc2); acc2 = fmaf(a[2][3].w, xv3.w, acc2);

      acc3 = fmaf(a[3][0].x, xv0.x, acc3); acc3 = fmaf(a[3][0].y, xv0.y, acc3);
      acc3 = fmaf(a[3][0].z, xv0.z, acc3); acc3 = fmaf(a[3][0].w, xv0.w, acc3);
      acc3 = fmaf(a[3][1].x, xv1.x, acc3); acc3 = fmaf(a[3][1].y, xv1.y, acc3);
      acc3 = fmaf(a[3][1].z, xv1.z, acc3); acc3 = fmaf(a[3][1].w, xv1.w, acc3);
      acc3 = fmaf(a[3][2].x, xv2.x, acc3); acc3 = fmaf(a[3][2].y, xv2.y, acc3);
      acc3 = fmaf(a[3][2].z, xv2.z, acc3); acc3 = fmaf(a[3][2].w, xv2.w, acc3);
      acc3 = fmaf(a[3][3].x, xv3.x, acc3); acc3 = fmaf(a[3][3].y, xv3.y, acc3);
      acc3 = fmaf(a[3][3].z, xv3.z, acc3); acc3 = fmaf(a[3][3].w, xv3.w, acc3);
    }

    // ---- all-DPP 8-part reduce (VALU pipe only) ----
    acc0 = dpp_add_f<0xB1>(acc0);   // quad_perm [1,0,3,2]  xor1
    acc1 = dpp_add_f<0xB1>(acc1);
    acc2 = dpp_add_f<0xB1>(acc2);
    acc3 = dpp_add_f<0xB1>(acc3);
    acc0 = dpp_add_f<0x4E>(acc0);   // quad_perm [2,3,0,1]  xor2
    acc1 = dpp_add_f<0x4E>(acc1);
    acc2 = dpp_add_f<0x4E>(acc2);
    acc3 = dpp_add_f<0x4E>(acc3);
    acc0 = dpp_add_f<0x114>(acc0);  // row_shr:4 — lanes 4..7 get quad0+quad1
    acc1 = dpp_add_f<0x114>(acc1);
    acc2 = dpp_add_f<0x114>(acc2);
    acc3 = dpp_add_f<0x114>(acc3);

    // tail lane p (4..7) owns row 4g + (p&3): static cndmask select tree
    float a01 = (p & 1) ? acc1 : acc0;
    float a23 = (p & 1) ? acc3 : acc2;
    float sum = (p & 2) ? a23 : a01;

    if (tail) {
      float zf = fmaf(b1, uv.y, fmaf(b0, uv.x, sum));
      zf = fminf(fmaxf(zf, -15.f), 15.f);
      float e = __builtin_amdgcn_exp2f(zf * 2.8853900817779268f);  // e^{2z}
      float xd = fmaf(-2.f, __builtin_amdgcn_rcpf(e + 1.f), 1.f);  // tanh(z)
      x_cur += (double)xd;
      dst[20 * (r >> 4) + (r & 15)] = (float)x_cur;
      double d = x_cur - (double)xr0;  // xr0 loaded 4 steps ago: long complete
      mse = fma(d, d, mse);
    }
    // raw barrier: drain only LDS ops; vmem prefetches stay in flight
    asm volatile("s_waitcnt lgkmcnt(0)" ::: "memory");
    __builtin_amdgcn_s_barrier();
    asm volatile("" ::: "memory");

    xr0 = xr1; xr1 = xr2; xr2 = xr3; xr3 = xnew;  // SSA-renamed by unroll
  };

#pragma unroll 1
  for (int s = 0; s < NSTEPS; s += 4) {
    step(xs0, xs1, s);
    step(xs1, xs0, s + 1);
    step(xs0, xs1, s + 2);
    step(xs1, xs0, s + 3);
  }

  // ---- final reduction of the MSE accumulator ----
#pragma unroll
  for (int off = 1; off < 64; off <<= 1) mse += __shfl_xor(mse, off, 64);
  if ((t & 63) == 0) wsum[t >> 6] = mse;
  __syncthreads();
  if (t == 0) {
    double tot = wsum[0] + wsum[1] + wsum[2] + wsum[3];
    out[0] = (float)(tot / (double)((NSTEPS + 1) * NX));
  }
}

extern "C" void kernel_launch(void* const* d_in, const int* in_sizes, int n_in,
                              void* d_out, int out_size, void* d_ws, size_t ws_size,
                              hipStream_t stream) {
  const float* x0 = (const float*)d_in[0];
  const float* xref = (const float*)d_in[1];
  const float* useq = (const float*)d_in[2];
  const float* A = (const float*)d_in[3];
  const float* B = (const float*)d_in[4];
  float* out = (float*)d_out;

  nmpc_rollout_kernel<<<dim3(1), dim3(256), 0, stream>>>(x0, xref, useq, A, B, out);
}

// Round 6
// 1322.569 us; speedup vs baseline: 1.3835x; 1.0970x over previous
//
#include <hip/hip_runtime.h>

#define NX 128
#define NSTEPS 4096

typedef float f2 __attribute__((ext_vector_type(2)));
typedef float f4 __attribute__((ext_vector_type(4)));

union F4 {
  f4 v;
  f2 h[2];
  float s[4];
};

// packed fp32 FMA: d = a*b + d on both 32-bit halves (full-rate on CDNA)
__device__ __forceinline__ void pk_fma(f2& d, f2 a, f2 b) {
  asm("v_pk_fma_f32 %0, %1, %2, %0" : "+v"(d) : "v"(a), "v"(b));
}

// v += DPP-moved v. bound_ctrl=false: invalid source lanes keep old value
// (harmless: only lanes p>=4 are consumed after the final stage).
template <int CTRL>
__device__ __forceinline__ float dpp_add_f(float v) {
  int i = __float_as_int(v);
  int s = __builtin_amdgcn_update_dpp(i, i, CTRL, 0xf, 0xf, false);
  return v + __int_as_float(s);
}

__launch_bounds__(256, 1)
__global__ void nmpc_rollout_kernel(const float* __restrict__ x0,
                                    const float* __restrict__ xref,
                                    const float* __restrict__ useq,
                                    const float* __restrict__ A,
                                    const float* __restrict__ B,
                                    float* __restrict__ out) {
  // x stored as 8 slices of 16 floats padded to 20 words (80B stride):
  // per ds_read_b128 the 8 broadcast groups start at banks
  // (20p)%32 = {0,20,8,28,16,4,24,12} -> disjoint bank quads, conflict-free.
  __shared__ __align__(16) float xs0[160];
  __shared__ __align__(16) float xs1[160];
  __shared__ float2 us[NSTEPS];  // interleaved (u0[s], u1[s]) pairs, 32KB
  __shared__ double wsum[4];

  const int t = threadIdx.x;
  const int g = t >> 3;        // row-group 0..31 (4 rows each)
  const int p = t & 7;         // column part 0..7 (16 cols each)
  const int j0 = p & 3;        // row-within-group owned by tail lanes
  const int r = 4 * g + j0;    // row index (valid 0..127 on every lane)
  const bool tail = (p >= 4);  // row_shr:4 delivers the full sum to lanes 4..7

  // ---- one-time staging of useq into LDS (interleaved pairs) ----
#pragma unroll
  for (int k = 0; k < NSTEPS / 256; ++k) {
    int idx = k * 256 + t;
    us[idx] = make_float2(useq[idx], useq[NSTEPS + idx]);
  }

  // ---- A fragment: rows 4g..4g+3, cols 16p..16p+15 -> 64 VGPRs ----
  F4 a[4][4];
#pragma unroll
  for (int j = 0; j < 4; ++j) {
#pragma unroll
    for (int q = 0; q < 4; ++q) {
      a[j][q].v = *(const f4*)(A + (4 * g + j) * NX + 16 * p + 4 * q);
    }
  }

  const float b0 = B[2 * r];
  const float b1 = B[2 * r + 1];

  // fp64 state on tail lanes; LDS holds the fp32 copy used by the matvec.
  double x_cur = (double)x0[r];
  double mse = 0.0;
  if (tail) {
    double d = x_cur - (double)xref[r];
    mse = d * d;
    xs0[20 * (r >> 4) + (r & 15)] = (float)x_cur;
  }
  asm volatile("s_waitcnt lgkmcnt(0)" ::: "memory");
  __builtin_amdgcn_s_barrier();
  asm volatile("" ::: "memory");

  // ---- 4-deep rolling prefetch of xref rows (consumed off the x-chain) ----
  float xr0 = xref[1 * NX + r];
  float xr1 = xref[2 * NX + r];
  float xr2 = xref[3 * NX + r];
  float xr3 = xref[4 * NX + r];

  auto step = [&](const float* __restrict__ src, float* __restrict__ dst, int s) {
    // ---- x slice first (FMA-critical; DS returns in-order) ----
    const f4* xb = (const f4*)(src + 20 * p);
    F4 xv0, xv1, xv2, xv3;
    xv0.v = xb[0]; xv1.v = xb[1]; xv2.v = xb[2]; xv3.v = xb[3];
    // u broadcast (consumed late, in tanh) and global prefetch refill
    float2 uv = us[s];
    int nref = (s + 5 <= NSTEPS) ? (s + 5) : NSTEPS;
    float xnew = xref[nref * NX + r];

    // ---- 4 rows x 16 cols via packed FMAs: 32 pk-fma, 8 indep chains ----
    f2 ae[4], ao[4];
#pragma unroll
    for (int j = 0; j < 4; ++j) { ae[j] = (f2)(0.f); ao[j] = (f2)(0.f); }
#pragma unroll
    for (int j = 0; j < 4; ++j) {
      pk_fma(ae[j], a[j][0].h[0], xv0.h[0]);
      pk_fma(ao[j], a[j][0].h[1], xv0.h[1]);
      pk_fma(ae[j], a[j][1].h[0], xv1.h[0]);
      pk_fma(ao[j], a[j][1].h[1], xv1.h[1]);
      pk_fma(ae[j], a[j][2].h[0], xv2.h[0]);
      pk_fma(ao[j], a[j][2].h[1], xv2.h[1]);
      pk_fma(ae[j], a[j][3].h[0], xv3.h[0]);
      pk_fma(ao[j], a[j][3].h[1], xv3.h[1]);
    }
    float acc0, acc1, acc2, acc3;
    {
      f2 h0 = ae[0] + ao[0];
      f2 h1 = ae[1] + ao[1];
      f2 h2 = ae[2] + ao[2];
      f2 h3 = ae[3] + ao[3];
      acc0 = h0.x + h0.y;
      acc1 = h1.x + h1.y;
      acc2 = h2.x + h2.y;
      acc3 = h3.x + h3.y;
    }

    // ---- all-DPP 8-part reduce (VALU pipe only) ----
    acc0 = dpp_add_f<0xB1>(acc0);   // quad_perm [1,0,3,2]  xor1
    acc1 = dpp_add_f<0xB1>(acc1);
    acc2 = dpp_add_f<0xB1>(acc2);
    acc3 = dpp_add_f<0xB1>(acc3);
    acc0 = dpp_add_f<0x4E>(acc0);   // quad_perm [2,3,0,1]  xor2
    acc1 = dpp_add_f<0x4E>(acc1);
    acc2 = dpp_add_f<0x4E>(acc2);
    acc3 = dpp_add_f<0x4E>(acc3);
    acc0 = dpp_add_f<0x114>(acc0);  // row_shr:4 — lanes 4..7 get quad0+quad1
    acc1 = dpp_add_f<0x114>(acc1);
    acc2 = dpp_add_f<0x114>(acc2);
    acc3 = dpp_add_f<0x114>(acc3);

    // tail lane p (4..7) owns row 4g + (p&3): static cndmask select tree
    float a01 = (p & 1) ? acc1 : acc0;
    float a23 = (p & 1) ? acc3 : acc2;
    float sum = (p & 2) ? a23 : a01;

    if (tail) {
      float zf = fmaf(b1, uv.y, fmaf(b0, uv.x, sum));
      // tanh(z) = 1 - 2/(e^{2z}+1); exp2 overflow/underflow saturates to +-1
      float e = __builtin_amdgcn_exp2f(zf * 2.8853900817779268f);
      float xd = fmaf(-2.f, __builtin_amdgcn_rcpf(e + 1.f), 1.f);
      x_cur += (double)xd;
      dst[20 * (r >> 4) + (r & 15)] = (float)x_cur;
      double d = x_cur - (double)xr0;  // xr0 loaded 4 steps ago: long complete
      mse = fma(d, d, mse);
    }
    // raw barrier: drain only LDS ops; vmem prefetches stay in flight
    asm volatile("s_waitcnt lgkmcnt(0)" ::: "memory");
    __builtin_amdgcn_s_barrier();
    asm volatile("" ::: "memory");

    xr0 = xr1; xr1 = xr2; xr2 = xr3; xr3 = xnew;  // SSA-renamed by unroll
  };

#pragma unroll 1
  for (int s = 0; s < NSTEPS; s += 4) {
    step(xs0, xs1, s);
    step(xs1, xs0, s + 1);
    step(xs0, xs1, s + 2);
    step(xs1, xs0, s + 3);
  }

  // ---- final reduction of the MSE accumulator ----
#pragma unroll
  for (int off = 1; off < 64; off <<= 1) mse += __shfl_xor(mse, off, 64);
  if ((t & 63) == 0) wsum[t >> 6] = mse;
  __syncthreads();
  if (t == 0) {
    double tot = wsum[0] + wsum[1] + wsum[2] + wsum[3];
    out[0] = (float)(tot / (double)((NSTEPS + 1) * NX));
  }
}

extern "C" void kernel_launch(void* const* d_in, const int* in_sizes, int n_in,
                              void* d_out, int out_size, void* d_ws, size_t ws_size,
                              hipStream_t stream) {
  const float* x0 = (const float*)d_in[0];
  const float* xref = (const float*)d_in[1];
  const float* useq = (const float*)d_in[2];
  const float* A = (const float*)d_in[3];
  const float* B = (const float*)d_in[4];
  float* out = (float*)d_out;

  nmpc_rollout_kernel<<<dim3(1), dim3(256), 0, stream>>>(x0, xref, useq, A, B, out);
}